// Round 3
// baseline (291.371 us; speedup 1.0000x reference)
//
#include <hip/hip_runtime.h>
#include <hip/hip_bf16.h>
#include <stdint.h>

typedef __bf16 bf16;
typedef __bf16 bf16x8 __attribute__((ext_vector_type(8)));
typedef float  f32x4  __attribute__((ext_vector_type(4)));

#define E   512
#define SB  4128           // per-batch extended row stride (4098 valid + 30 pad) -> M1 = 129*256
#define M1  (8 * SB)       // 33024
#define M2  32768

__device__ __forceinline__ void gl_lds_16(const bf16* g, bf16* l) {
    __builtin_amdgcn_global_load_lds(
        (__attribute__((address_space(1))) void*)g,
        (__attribute__((address_space(3))) void*)l, 16, 0, 0);
}

// ---------------------------------------------------------------------------
// Weight-resident GEMM: C[m,n] = sum_k A[m,k] * W[n,k].
// Block: 256 rows x 64 cols. W-slice (64x512 bf16 = 64KB) staged to LDS ONCE,
// tiled [kt(16)][n(64)][kc(32)] so B-frags are conflict-mild ds_read_b128.
// K-loop has NO barriers: A-frags stream global->VGPR with 1-step prefetch.
// GATHER=1: A row gathered with per-head shift (head = k>>6, pattern [0,-1,1,0]).
// ---------------------------------------------------------------------------
template<int GATHER, int OUT_BF16>
__global__ __launch_bounds__(256, 2)
void gemm_wres(const bf16* __restrict__ A, const bf16* __restrict__ W,
               bf16* __restrict__ Cb, float* __restrict__ Cf)
{
    __shared__ bf16 Ws[16 * 2048];       // 64 KB
    const int tid  = threadIdx.x;
    const int bn   = blockIdx.x;         // 0..7  (64-col slices)
    const int bm   = blockIdx.y;         // 256-row chunks
    const int wave = tid >> 6, lane = tid & 63;
    const int n0   = bn * 64;

    // stage W rows n0..n0+63 (all K) into tiled LDS layout
#pragma unroll
    for (int i = 0; i < 16; ++i) {
        const int c  = i * 256 + tid;    // 16B-chunk id, 4096 total
        const int kt = c >> 8;
        const int r  = (c >> 2) & 63;
        const int kc = (c & 3) << 3;
        gl_lds_16(W + (size_t)(n0 + r) * E + (kt << 5) + kc, Ws + c * 8);
    }
    __syncthreads();                     // only barrier in the kernel

    const int fr = lane & 15, ks = (lane >> 4) << 3;
    const int mbase = bm * 256 + wave * 64;

    f32x4 acc[4][4] = {};

    long arow[4];
#pragma unroll
    for (int i = 0; i < 4; ++i) {
        const int m = mbase + i * 16 + fr;
        arow[i] = GATHER ? (long)((m >> 12) * SB + (m & 4095) + 1) : (long)m;
    }

    bf16x8 a_cur[4], a_nxt[4];
#pragma unroll
    for (int i = 0; i < 4; ++i)          // k=0: head 0 -> shift 0
        a_cur[i] = *(const bf16x8*)(A + arow[i] * E + ks);

#pragma unroll
    for (int kt = 0; kt < 16; ++kt) {
        if (kt < 15) {                   // prefetch next K-step's A-frags
            const int k0n = (kt + 1) * 32;
            int sh = 0;
            if (GATHER) { const int h3 = (k0n >> 6) & 3; sh = (h3 == 1) ? -1 : (h3 == 2) ? 1 : 0; }
#pragma unroll
            for (int i = 0; i < 4; ++i)
                a_nxt[i] = *(const bf16x8*)(A + (arow[i] + sh) * E + k0n + ks);
        }
        bf16x8 bfrg[4];
#pragma unroll
        for (int j = 0; j < 4; ++j)
            bfrg[j] = *(const bf16x8*)(Ws + kt * 2048 + (j * 16 + fr) * 32 + ks);
#pragma unroll
        for (int i = 0; i < 4; ++i)
#pragma unroll
            for (int j = 0; j < 4; ++j)
                acc[i][j] = __builtin_amdgcn_mfma_f32_16x16x32_bf16(a_cur[i], bfrg[j], acc[i][j], 0, 0, 0);
#pragma unroll
        for (int i = 0; i < 4; ++i) a_cur[i] = a_nxt[i];
    }

    // epilogue: C/D layout col = lane&15, row = (lane>>4)*4 + reg
    const int crow = (lane >> 4) << 2;
    const int ccol = lane & 15;
    const int row0 = mbase + crow;
    const int col0 = n0 + ccol;
#pragma unroll
    for (int i = 0; i < 4; ++i)
#pragma unroll
        for (int j = 0; j < 4; ++j)
#pragma unroll
            for (int r = 0; r < 4; ++r) {
                const size_t idx = (size_t)(row0 + i * 16 + r) * E + (col0 + j * 16);
                if (OUT_BF16) Cb[idx] = (bf16)acc[i][j][r];
                else          Cf[idx] = acc[i][j][r];
            }
}

// ------- prefilter: VG[b, r, :] = sum_j filt[j] * values[b, r-3+j, :] -------
// r in [0,SB); valid s' = r-1 in [-1,4096]; rows r>=4098 written as zero.
// Fuses fp32->bf16 conversion. One thread per 8 channels.
__global__ __launch_bounds__(256)
void prefilter(const float* __restrict__ vals, bf16* __restrict__ vg)
{
    const int b   = blockIdx.y;
    const int idx = blockIdx.x * 256 + threadIdx.x;    // [0, SB*64)
    const int e8  = idx & 63;
    const int r   = idx >> 6;

    float acc[8] = {0.f, 0.f, 0.f, 0.f, 0.f, 0.f, 0.f, 0.f};
    if (r < 4098) {
        const float filt[5] = {0.05399096651318806f, 0.24197072451914337f,
                               0.3989422804014327f,
                               0.24197072451914337f, 0.05399096651318806f};
#pragma unroll
        for (int j = 0; j < 5; ++j) {
            const int sp = r - 3 + j;
            if (sp >= 0 && sp < 4096) {
                const f32x4* p = (const f32x4*)(vals + ((size_t)(b * 4096 + sp)) * E + e8 * 8);
                f32x4 x0 = p[0], x1 = p[1];
                const float w = filt[j];
                acc[0] += w * x0[0]; acc[1] += w * x0[1];
                acc[2] += w * x0[2]; acc[3] += w * x0[3];
                acc[4] += w * x1[0]; acc[5] += w * x1[1];
                acc[6] += w * x1[2]; acc[7] += w * x1[3];
            }
        }
    }
    bf16x8 o;
#pragma unroll
    for (int d = 0; d < 8; ++d) o[d] = (bf16)acc[d];
    ((bf16x8*)vg)[(size_t)b * (SB * 64) + idx] = o;
}

// ------- weight convert: both 512x512 fp32 matrices -> bf16 in one launch -----
__global__ __launch_bounds__(256)
void cvt_weights(const float* __restrict__ w_in, const float* __restrict__ w_out,
                 bf16* __restrict__ win_b, bf16* __restrict__ wout_b)
{
    const int i = blockIdx.x * 256 + threadIdx.x;      // [0, 2*512*512/8)
    const int half = (E * E) / 8;
    const float* src = (i < half) ? w_in : w_out;
    bf16* dst        = (i < half) ? win_b : wout_b;
    const int k = (i < half) ? i : i - half;
    const f32x4* p = (const f32x4*)src + 2 * (size_t)k;
    f32x4 a = p[0], bq = p[1];
    bf16x8 o;
    o[0] = (bf16)a[0]; o[1] = (bf16)a[1]; o[2] = (bf16)a[2]; o[3] = (bf16)a[3];
    o[4] = (bf16)bq[0]; o[5] = (bf16)bq[1]; o[6] = (bf16)bq[2]; o[7] = (bf16)bq[3];
    *((bf16x8*)dst + k) = o;
}

extern "C" void kernel_launch(void* const* d_in, const int* in_sizes, int n_in,
                              void* d_out, int out_size, void* d_ws, size_t ws_size,
                              hipStream_t stream)
{
    const float* values = (const float*)d_in[0];
    // d_in[1]=keys, d_in[2]=queries: unused by the reference path (no QK^T)
    const float* w_in   = (const float*)d_in[3];
    const float* w_out  = (const float*)d_in[4];
    float* out = (float*)d_out;

    // ws: weights 1MB + P 33.8MB.  VG lives in d_out's tail (overwritten by GEMM2 at the end).
    bf16* win_b  = (bf16*)d_ws;                 // 512*512
    bf16* wout_b = win_b + E * E;               // 512*512
    bf16* Pbuf   = wout_b + E * E;              // M1*E bf16 (33.8 MB)
    bf16* vg     = (bf16*)d_out;                // M1*E bf16 (33.8 MB) inside 64MB d_out

    cvt_weights<<<(2 * E * E / 8) / 256, 256, 0, stream>>>(w_in, w_out, win_b, wout_b);
    prefilter<<<dim3(SB * 64 / 256, 8), 256, 0, stream>>>(values, vg);

    gemm_wres<0, 1><<<dim3(8, M1 / 256), 256, 0, stream>>>(vg, win_b, Pbuf, nullptr);
    gemm_wres<1, 0><<<dim3(8, M2 / 256), 256, 0, stream>>>(Pbuf, wout_b, nullptr, out);
}